// Round 10
// baseline (328.307 us; speedup 1.0000x reference)
//
#include <hip/hip_runtime.h>
#include <hip/hip_fp16.h>

#define N_NODES 50000
#define N_EDGES 1600000
#define NB 196                    // buckets: dst>>8
#define NBLK_H 256                // hist blocks
#define CHUNK_H (N_EDGES / NBLK_H)   // 6250
#define NBLK_S 512                // scatter blocks
#define CHUNK_S (N_EDGES / NBLK_S)   // 3125
#define GEMM_BLOCKS 256
#define HPLANE (N_NODES * 32)     // f16 elements per head plane

typedef _Float16 half8_t __attribute__((ext_vector_type(8)));
typedef float floatx4 __attribute__((ext_vector_type(4)));

// ---- standalone bucket histogram (totals only) ----------------------------
__global__ __launch_bounds__(256) void edge_hist(const int* __restrict__ dst,
                                                 int* __restrict__ totals) {
    __shared__ int hist[NB];
    int t = threadIdx.x, b = blockIdx.x;
    if (t < NB) hist[t] = 0;
    __syncthreads();
    int s = b * CHUNK_H;
    for (int i = t; i < CHUNK_H; i += 256)
        atomicAdd(&hist[dst[s + i] >> 8], 1);
    __syncthreads();
    if (t < NB && hist[t]) atomicAdd(&totals[t], hist[t]);
}

// ---- MFMA f16 GEMM (persistent, head-major outputs) ∥ optional scatter ----
__global__ __launch_bounds__(256) void gemm_mfma(const float* __restrict__ Xf,
                                                 const __half* __restrict__ Xh,
                                                 int in_half,
                                                 const float* __restrict__ W,
                                                 const float* __restrict__ att_s,
                                                 const float* __restrict__ att_d,
                                                 __half* __restrict__ Hh,
                                                 float* __restrict__ ash,
                                                 float* __restrict__ adh, int nrows,
                                                 const int* __restrict__ e_src,
                                                 const int* __restrict__ e_dst,
                                                 const int* __restrict__ btotal,
                                                 int* __restrict__ bcursor,
                                                 int* __restrict__ bucketed,
                                                 int with_scatter) {
    __shared__ __align__(16) char lds[49152];   // GEMM: A[0,16K) Wt[16K,48K)
    int t = threadIdx.x;
    // ---- scatter role: LDS-reorder + coalesced bucket-run writes ----
    if (with_scatter && blockIdx.x >= GEMM_BLOCKS) {
        int* recs   = reinterpret_cast<int*>(lds);            // 3125 ints
        int* srt    = reinterpret_cast<int*>(lds + 12800);    // 3125 ints
        int* bexcl  = reinterpret_cast<int*>(lds + 25600);    // NB
        int* hist   = reinterpret_cast<int*>(lds + 26624);    // NB
        int* lstart = reinterpret_cast<int*>(lds + 27648);    // NB
        int* curL   = reinterpret_cast<int*>(lds + 28672);    // NB
        int* gbase  = reinterpret_cast<int*>(lds + 29696);    // NB
        int b = blockIdx.x - GEMM_BLOCKS;
        int myTot = 0;
        if (t < NB) { myTot = btotal[t]; bexcl[t] = myTot; hist[t] = 0; }
        __syncthreads();
        for (int o = 1; o < NB; o <<= 1) {       // scan of global bucket totals
            int v = (t < NB && t >= o) ? bexcl[t - o] : 0;
            __syncthreads();
            if (t < NB) bexcl[t] += v;
            __syncthreads();
        }
        if (t < NB) bexcl[t] -= myTot;           // inclusive -> exclusive
        int s0 = b * CHUNK_S;
        for (int i = t; i < CHUNK_S; i += 256) {
            unsigned sv = (unsigned)e_src[s0 + i], dv = (unsigned)e_dst[s0 + i];
            recs[i] = (int)((sv << 16) | dv);
            atomicAdd(&hist[dv >> 8], 1);
        }
        __syncthreads();
        int myCnt = (t < NB) ? hist[t] : 0;
        if (t < NB) lstart[t] = myCnt;
        __syncthreads();
        for (int o = 1; o < NB; o <<= 1) {       // scan of block-local hist
            int v = (t < NB && t >= o) ? lstart[t - o] : 0;
            __syncthreads();
            if (t < NB) lstart[t] += v;
            __syncthreads();
        }
        if (t < NB) {
            int ex = lstart[t] - myCnt;
            lstart[t] = ex;
            curL[t] = ex;
            gbase[t] = bexcl[t] + atomicAdd(&bcursor[t], myCnt);
        }
        __syncthreads();
        for (int i = t; i < CHUNK_S; i += 256) { // LDS reorder by bucket
            int r = recs[i];
            int bk = (int)(((unsigned)r & 0xFFFFu) >> 8);
            int p = atomicAdd(&curL[bk], 1);
            srt[p] = r;
        }
        __syncthreads();
        for (int p = t; p < CHUNK_S; p += 256) { // coalesced run writes
            int r = srt[p];
            unsigned d = (unsigned)r & 0xFFFFu;
            int bk = (int)(d >> 8);
            int g = gbase[bk] + (p - lstart[bk]);
            bucketed[g] = (int)((((unsigned)r >> 16) << 8) | (d & 255u));
        }
        return;
    }
    // ---- GEMM role ----
    char* Alds = lds;
    char* Wlds = lds + 16384;
    int lane = t & 63, wv_ = t >> 6;
    for (int p = 0; p < 16; ++p) {           // stage Wt[n][k] f16 swizzled, once
        int flat = p * 256 + t;
        int k = flat >> 5;
        int n0 = (flat & 31) * 4;
        float4 wv = reinterpret_cast<const float4*>(W)[flat];
        const float* wf = reinterpret_cast<const float*>(&wv);
        #pragma unroll
        for (int i = 0; i < 4; ++i) {
            int n = n0 + i;
            int byte = (n * 256 + k * 2) ^ ((n & 7) << 4);
            *reinterpret_cast<__half*>(Wlds + byte) = __float2half(wf[i]);
        }
    }
    int col16 = lane & 15;
    float Asv[8], Adv[8];
    #pragma unroll
    for (int nt = 0; nt < 8; ++nt) {
        Asv[nt] = att_s[nt * 16 + col16];
        Adv[nt] = att_d[nt * 16 + col16];
    }
    int ksub = (lane >> 4) * 16;
    int rloc = wv_ * 16 + col16;
    int ntiles = (nrows + 63) / 64;
    for (int tile = blockIdx.x; tile < ntiles; tile += GEMM_BLOCKS) {
        int row0 = tile * 64;
        __syncthreads();
        for (int p = 0; p < 8; ++p) {
            int r = p * 8 + (t >> 5);
            int f4 = t & 31;
            int rr = row0 + r;
            uint2 hv = make_uint2(0, 0);
            if (rr < nrows) {
                if (in_half) {
                    int col0 = f4 * 4;     // head-major input: plane col0>>5
                    hv = *reinterpret_cast<const uint2*>(
                        Xh + (size_t)(col0 >> 5) * HPLANE + (size_t)rr * 32 + (col0 & 31));
                } else {
                    float4 xv = reinterpret_cast<const float4*>(Xf)[(size_t)rr * 32 + f4];
                    __half2* hp = reinterpret_cast<__half2*>(&hv);
                    hp[0] = __floats2half2_rn(xv.x, xv.y);
                    hp[1] = __floats2half2_rn(xv.z, xv.w);
                }
            }
            int byte = (r * 256 + f4 * 8) ^ ((r & 7) << 4);
            *reinterpret_cast<uint2*>(Alds + byte) = hv;
        }
        __syncthreads();
        half8_t afr[4];
        #pragma unroll
        for (int kb = 0; kb < 4; ++kb) {
            int byte = (rloc * 256 + kb * 64 + ksub) ^ ((rloc & 7) << 4);
            afr[kb] = *reinterpret_cast<half8_t*>(Alds + byte);
        }
        floatx4 acc[8];
        #pragma unroll
        for (int nt = 0; nt < 8; ++nt) {
            int n = nt * 16 + col16;
            floatx4 a = {0.f, 0.f, 0.f, 0.f};
            #pragma unroll
            for (int kb = 0; kb < 4; ++kb) {
                int byte = (n * 256 + kb * 64 + ksub) ^ ((n & 7) << 4);
                half8_t bfr = *reinterpret_cast<half8_t*>(Wlds + byte);
                a = __builtin_amdgcn_mfma_f32_16x16x32_f16(afr[kb], bfr, a, 0, 0, 0);
            }
            acc[nt] = a;
        }
        float ps[4][4], pd[4][4];
        #pragma unroll
        for (int reg = 0; reg < 4; ++reg)
            #pragma unroll
            for (int h = 0; h < 4; ++h) {
                ps[reg][h] = acc[2*h][reg] * Asv[2*h] + acc[2*h+1][reg] * Asv[2*h+1];
                pd[reg][h] = acc[2*h][reg] * Adv[2*h] + acc[2*h+1][reg] * Adv[2*h+1];
            }
        #pragma unroll
        for (int m = 1; m <= 8; m <<= 1)
            #pragma unroll
            for (int reg = 0; reg < 4; ++reg)
                #pragma unroll
                for (int h = 0; h < 4; ++h) {
                    ps[reg][h] += __shfl_xor(ps[reg][h], m);
                    pd[reg][h] += __shfl_xor(pd[reg][h], m);
                }
        int rbase = row0 + wv_ * 16 + (lane >> 4) * 4;
        #pragma unroll
        for (int reg = 0; reg < 4; ++reg) {
            int grow = rbase + reg;
            if (grow < nrows) {
                #pragma unroll
                for (int nt = 0; nt < 8; ++nt) {
                    int col = nt * 16 + col16;
                    Hh[(size_t)(col >> 5) * HPLANE + (size_t)grow * 32 + (col & 31)] =
                        __float2half(acc[nt][reg]);
                }
                if (col16 == 0) {
                    #pragma unroll
                    for (int h = 0; h < 4; ++h) {
                        ash[(size_t)h * N_NODES + grow] = ps[reg][h];
                        adh[(size_t)h * N_NODES + grow] = pd[reg][h];
                    }
                }
            }
        }
    }
}

// ---- phase B: within-bucket counting sort by dst; emits off[] -------------
__global__ __launch_bounds__(1024) void bucket_sort(const int* __restrict__ bucketed,
                                                    const int* __restrict__ btotal,
                                                    int* __restrict__ sorted_packed,
                                                    int* __restrict__ off) {
    __shared__ int bb[NB];
    __shared__ int cnt[256], scn[256], cur[256];
    int t = threadIdx.x, k = blockIdx.x;
    if (t < NB) bb[t] = btotal[t];
    if (t < 256) cnt[t] = 0;
    __syncthreads();
    for (int o = 1; o < NB; o <<= 1) {
        int v = (t < NB && t >= o) ? bb[t - o] : 0;
        __syncthreads();
        if (t < NB) bb[t] += v;
        __syncthreads();
    }
    int base = (k == 0) ? 0 : bb[k - 1];
    int end  = bb[k];
    int m = end - base;
    for (int i = t; i < m; i += 1024)
        atomicAdd(&cnt[bucketed[base + i] & 255], 1);
    __syncthreads();
    if (t < 256) scn[t] = cnt[t];
    __syncthreads();
    for (int o = 1; o < 256; o <<= 1) {
        int v = (t < 256 && t >= o) ? scn[t - o] : 0;
        __syncthreads();
        if (t < 256) scn[t] += v;
        __syncthreads();
    }
    if (t < 256) {
        int excl = scn[t] - cnt[t];
        cur[t] = base + excl;
        int node = k * 256 + t;
        if (node <= N_NODES) off[node] = base + excl;
    }
    __syncthreads();
    for (int i = t; i < m; i += 1024) {
        int rec = bucketed[base + i];
        int p = atomicAdd(&cur[rec & 255], 1);
        sorted_packed[p] = rec;
    }
}

// ---- per-head aggregate: wave=(node,head), 4 lanes/edge, 16 edges/iter ----
// Head plane (3.2 MB) + score slice (0.2 MB) fit a 4 MB XCD L2 -> no
// capacity misses. Pass-major wave order keeps all CUs on one plane.
__global__ __launch_bounds__(256) void gat_aggregate_h(const __half* __restrict__ Hh,
                                                       const int* __restrict__ off,
                                                       const int* __restrict__ packed,
                                                       const float* __restrict__ ash,
                                                       const float* __restrict__ adh,
                                                       const float* __restrict__ bias,
                                                       float* __restrict__ OUTF,
                                                       __half* __restrict__ OUTH,
                                                       int mode) {
    int w = (blockIdx.x * 256 + threadIdx.x) >> 6;   // 0 .. 4*N-1, pass-major
    int lane = threadIdx.x & 63;
    int p = w / N_NODES;          // head
    int wid = w - p * N_NODES;    // node
    int s = off[wid], e = off[wid + 1];
    int q = lane >> 2;            // edge slot 0..15
    int sub = lane & 3;           // 16B chunk of the 64B head-row
    const char* Hc = reinterpret_cast<const char*>(Hh) + (size_t)p * (N_NODES * 64);
    const float* As = ash + (size_t)p * N_NODES;
    float adv = adh[(size_t)p * N_NODES + wid];
    float acc[8] = {0, 0, 0, 0, 0, 0, 0, 0};
    float den = 0.f;
    if (s < e) {
        int ii = s + q;
        int jj = ii < e ? ii : s;
        int sidx = __builtin_nontemporal_load(packed + jj) >> 8;   // src
        float sc = As[sidx];
        int rowb = sidx << 6;
        for (int i = s; i < e; i += 16) {
            uint4 hv = *reinterpret_cast<const uint4*>(Hc + rowb + sub * 16);
            float ev = sc + adv; ev = fmaxf(ev, 0.2f * ev);
            float w0 = (i + q < e) ? __expf(ev) : 0.f;
            int ii2 = i + 16 + q;                 // prefetch next slot
            int jj2 = ii2 < e ? ii2 : s;
            sidx = __builtin_nontemporal_load(packed + jj2) >> 8;
            sc = As[sidx];
            rowb = sidx << 6;
            den += w0;
            const __half2* ph = reinterpret_cast<const __half2*>(&hv);
            #pragma unroll
            for (int j = 0; j < 4; ++j) {
                float2 f = __half22float2(ph[j]);
                acc[2*j]   += w0 * f.x;
                acc[2*j+1] += w0 * f.y;
            }
        }
    }
    #pragma unroll
    for (int m = 4; m <= 32; m <<= 1) {
        #pragma unroll
        for (int j = 0; j < 8; ++j) acc[j] += __shfl_xor(acc[j], m);
        den += __shfl_xor(den, m);
    }
    if (q == 0) {                 // lanes 0..3 hold the reduced 32 cols
        float inv = den > 0.f ? 1.f / den : 0.f;
        float4 b0 = *reinterpret_cast<const float4*>(bias + p * 32 + sub * 8);
        float4 b1 = *reinterpret_cast<const float4*>(bias + p * 32 + sub * 8 + 4);
        float o[8];
        o[0] = acc[0]*inv + b0.x; o[1] = acc[1]*inv + b0.y;
        o[2] = acc[2]*inv + b0.z; o[3] = acc[3]*inv + b0.w;
        o[4] = acc[4]*inv + b1.x; o[5] = acc[5]*inv + b1.y;
        o[6] = acc[6]*inv + b1.z; o[7] = acc[7]*inv + b1.w;
        if (mode) {               // relu + f16, head-major (next layer's input)
            uint4 u;
            __half2* up = reinterpret_cast<__half2*>(&u);
            #pragma unroll
            for (int j = 0; j < 4; ++j)
                up[j] = __floats2half2_rn(fmaxf(o[2*j], 0.f), fmaxf(o[2*j+1], 0.f));
            *reinterpret_cast<uint4*>(OUTH + (size_t)p * HPLANE + (size_t)wid * 32 + sub * 8) = u;
        } else {                  // f32 standard [N,128]
            *reinterpret_cast<float4*>(OUTF + (size_t)wid * 128 + p * 32 + sub * 8) =
                make_float4(o[0], o[1], o[2], o[3]);
            *reinterpret_cast<float4*>(OUTF + (size_t)wid * 128 + p * 32 + sub * 8 + 4) =
                make_float4(o[4], o[5], o[6], o[7]);
        }
    }
}

// ---------------------------------------------------------------------------
extern "C" void kernel_launch(void* const* d_in, const int* in_sizes, int n_in,
                              void* d_out, int out_size, void* d_ws, size_t ws_size,
                              hipStream_t stream) {
    const float* x        = (const float*)d_in[0];
    const int*   edge     = (const int*)d_in[1];
    const float* W0       = (const float*)d_in[2];
    const float* att_src0 = (const float*)d_in[3];
    const float* att_dst0 = (const float*)d_in[4];
    const float* b0       = (const float*)d_in[5];
    const float* W1       = (const float*)d_in[6];
    const float* att_src1 = (const float*)d_in[7];
    const float* att_dst1 = (const float*)d_in[8];
    const float* b1       = (const float*)d_in[9];
    const int* src = edge;
    const int* dst = edge + N_EDGES;
    float* out = (float*)d_out;

    char* ws = (char*)d_ws;
    size_t o = 0;
    auto alloc = [&](size_t bytes) { char* p = ws + o; o += (bytes + 255) & ~(size_t)255; return p; };
    __half* Hh    = (__half*)alloc((size_t)N_NODES * 128 * 2);    // 12.8 MB head-major
    float* ash    = (float*)alloc((size_t)4 * N_NODES * 4);       // [4][N]
    float* adh    = (float*)alloc((size_t)4 * N_NODES * 4);       // [4][N]
    int*   off    = (int*)alloc((size_t)(N_NODES + 1) * 4);
    int*   sorted = (int*)alloc((size_t)N_EDGES * 4);             // 6.4 MB
    // overlay: sort temps, later reused as the f16 head-major layer-0 output
    size_t mark = o;
    int*   btot2    = (int*)alloc((size_t)2 * NB * 4);            // btotal | bcursor
    int*   bucketed = (int*)alloc((size_t)N_EDGES * 4);           // 6.4 MB
    o = mark + (size_t)N_NODES * 128 * 2;                         // reserve h1 region
    __half* h1h = (__half*)(ws + mark);                           // 12.8 MB, aliases temps
    int* btotal  = btot2;
    int* bcursor = btot2 + NB;

    // ---- zero bucket totals/cursors, then hist ----
    hipMemsetAsync(btot2, 0, (size_t)2 * NB * 4, stream);
    edge_hist<<<NBLK_H, 256, 0, stream>>>(dst, btotal);

    // ---- layer-0 GEMM running concurrently with the bucket scatter ----
    gemm_mfma<<<GEMM_BLOCKS + NBLK_S, 256, 0, stream>>>(x, (const __half*)nullptr, 0,
                                                        W0, att_src0, att_dst0,
                                                        Hh, ash, adh, N_NODES,
                                                        src, dst, btotal, bcursor, bucketed, 1);
    // ---- within-bucket sort (emits off[]) ----
    bucket_sort<<<NB, 1024, 0, stream>>>(bucketed, btotal, sorted, off);

    // ---- layer 0 aggregate (relu, f16 head-major) ----
    gat_aggregate_h<<<N_NODES, 256, 0, stream>>>(Hh, off, sorted, ash, adh, b0,
                                                 (float*)nullptr, h1h, 1);

    // ---- layer 1 ----
    gemm_mfma<<<GEMM_BLOCKS, 256, 0, stream>>>((const float*)nullptr, h1h, 1,
                                               W1, att_src1, att_dst1,
                                               Hh, ash, adh, N_NODES,
                                               (const int*)nullptr, (const int*)nullptr,
                                               (const int*)nullptr, (int*)nullptr, (int*)nullptr, 0);
    gat_aggregate_h<<<N_NODES, 256, 0, stream>>>(Hh, off, sorted, ash, adh, b1,
                                                 out, (__half*)nullptr, 0);
}

// Round 11
// 189.709 us; speedup vs baseline: 1.7306x; 1.7306x over previous
//
#include <hip/hip_runtime.h>
#include <hip/hip_fp16.h>

#define N_NODES 50000
#define N_EDGES 1600000
#define NB 196                    // buckets: dst>>8
#define CAP 8960                  // fixed per-bucket capacity (mean 8163 + 8.8 sigma)
#define NBLK_S 512                // scatter blocks
#define CHUNK_S (N_EDGES / NBLK_S)   // 3125
#define GEMM_BLOCKS 256

typedef _Float16 half8_t __attribute__((ext_vector_type(8)));
typedef _Float16 half2_t __attribute__((ext_vector_type(2)));
typedef float floatx4 __attribute__((ext_vector_type(4)));

#if defined(__has_builtin)
#  if __has_builtin(__builtin_amdgcn_fdot2)
#    define HAS_FDOT2 1
#  endif
#endif
#ifndef HAS_FDOT2
#  define HAS_FDOT2 0
#endif

// ---- MFMA f16 GEMM (persistent) + score epilogue, ∥ bucket scatter --------
__global__ __launch_bounds__(256) void gemm_mfma(const float* __restrict__ Xf,
                                                 const __half* __restrict__ Xh,
                                                 int in_half,
                                                 const float* __restrict__ W,
                                                 const float* __restrict__ att_s,
                                                 const float* __restrict__ att_d,
                                                 __half* __restrict__ H16,
                                                 float* __restrict__ as_out,
                                                 float* __restrict__ ad_out, int nrows,
                                                 const int* __restrict__ e_src,
                                                 const int* __restrict__ e_dst,
                                                 int* __restrict__ bcursor,
                                                 int* __restrict__ bucketed,
                                                 int with_scatter) {
    __shared__ __align__(16) char lds[49152];   // GEMM: A[0,16K) Wt[16K,48K)
    int t = threadIdx.x;
    // ---- scatter role: LDS-reorder + coalesced fixed-stride run writes ----
    if (with_scatter && blockIdx.x >= GEMM_BLOCKS) {
        int* recs   = reinterpret_cast<int*>(lds);            // 3125 ints
        int* srt    = reinterpret_cast<int*>(lds + 12800);    // 3125 ints
        int* hist   = reinterpret_cast<int*>(lds + 25600);    // NB
        int* lstart = reinterpret_cast<int*>(lds + 26624);    // NB
        int* curL   = reinterpret_cast<int*>(lds + 27648);    // NB
        int* gbase  = reinterpret_cast<int*>(lds + 28672);    // NB
        int b = blockIdx.x - GEMM_BLOCKS;
        if (t < NB) hist[t] = 0;
        __syncthreads();
        int s0 = b * CHUNK_S;
        for (int i = t; i < CHUNK_S; i += 256) {
            unsigned sv = (unsigned)e_src[s0 + i], dv = (unsigned)e_dst[s0 + i];
            recs[i] = (int)((sv << 16) | dv);
            atomicAdd(&hist[dv >> 8], 1);
        }
        __syncthreads();
        int myCnt = (t < NB) ? hist[t] : 0;
        if (t < NB) lstart[t] = myCnt;
        __syncthreads();
        for (int o = 1; o < NB; o <<= 1) {       // scan of block-local hist
            int v = (t < NB && t >= o) ? lstart[t - o] : 0;
            __syncthreads();
            if (t < NB) lstart[t] += v;
            __syncthreads();
        }
        if (t < NB) {
            int ex = lstart[t] - myCnt;
            lstart[t] = ex;
            curL[t] = ex;
            gbase[t] = t * CAP + atomicAdd(&bcursor[t], myCnt);  // claim run
        }
        __syncthreads();
        for (int i = t; i < CHUNK_S; i += 256) { // LDS reorder by bucket
            int r = recs[i];
            int bk = (int)(((unsigned)r & 0xFFFFu) >> 8);
            int p = atomicAdd(&curL[bk], 1);
            srt[p] = r;
        }
        __syncthreads();
        for (int p = t; p < CHUNK_S; p += 256) { // coalesced run writes
            int r = srt[p];
            unsigned d = (unsigned)r & 0xFFFFu;
            int bk = (int)(d >> 8);
            int g = gbase[bk] + (p - lstart[bk]);
            bucketed[g] = (int)((((unsigned)r >> 16) << 8) | (d & 255u));
        }
        return;
    }
    // ---- GEMM role ----
    char* Alds = lds;
    char* Wlds = lds + 16384;
    int lane = t & 63, wv_ = t >> 6;
    for (int p = 0; p < 16; ++p) {           // stage Wt[n][k] f16 swizzled, once
        int flat = p * 256 + t;
        int k = flat >> 5;
        int n0 = (flat & 31) * 4;
        float4 wv = reinterpret_cast<const float4*>(W)[flat];
        const float* wf = reinterpret_cast<const float*>(&wv);
        #pragma unroll
        for (int i = 0; i < 4; ++i) {
            int n = n0 + i;
            int byte = (n * 256 + k * 2) ^ ((n & 7) << 4);
            *reinterpret_cast<__half*>(Wlds + byte) = __float2half(wf[i]);
        }
    }
    int col16 = lane & 15;
    float Asv[8], Adv[8];
    #pragma unroll
    for (int nt = 0; nt < 8; ++nt) {
        Asv[nt] = att_s[nt * 16 + col16];
        Adv[nt] = att_d[nt * 16 + col16];
    }
    int ksub = (lane >> 4) * 16;
    int rloc = wv_ * 16 + col16;
    int ntiles = (nrows + 63) / 64;
    for (int tile = blockIdx.x; tile < ntiles; tile += GEMM_BLOCKS) {
        int row0 = tile * 64;
        __syncthreads();
        for (int p = 0; p < 8; ++p) {
            int r = p * 8 + (t >> 5);
            int f4 = t & 31;
            int rr = row0 + r;
            uint2 hv = make_uint2(0, 0);
            if (rr < nrows) {
                if (in_half) {
                    hv = *reinterpret_cast<const uint2*>(Xh + (size_t)rr * 128 + f4 * 4);
                } else {
                    float4 xv = reinterpret_cast<const float4*>(Xf)[(size_t)rr * 32 + f4];
                    __half2* hp = reinterpret_cast<__half2*>(&hv);
                    hp[0] = __floats2half2_rn(xv.x, xv.y);
                    hp[1] = __floats2half2_rn(xv.z, xv.w);
                }
            }
            int byte = (r * 256 + f4 * 8) ^ ((r & 7) << 4);
            *reinterpret_cast<uint2*>(Alds + byte) = hv;
        }
        __syncthreads();
        half8_t afr[4];
        #pragma unroll
        for (int kb = 0; kb < 4; ++kb) {
            int byte = (rloc * 256 + kb * 64 + ksub) ^ ((rloc & 7) << 4);
            afr[kb] = *reinterpret_cast<half8_t*>(Alds + byte);
        }
        floatx4 acc[8];
        #pragma unroll
        for (int nt = 0; nt < 8; ++nt) {
            int n = nt * 16 + col16;
            floatx4 a = {0.f, 0.f, 0.f, 0.f};
            #pragma unroll
            for (int kb = 0; kb < 4; ++kb) {
                int byte = (n * 256 + kb * 64 + ksub) ^ ((n & 7) << 4);
                half8_t bfr = *reinterpret_cast<half8_t*>(Wlds + byte);
                a = __builtin_amdgcn_mfma_f32_16x16x32_f16(afr[kb], bfr, a, 0, 0, 0);
            }
            acc[nt] = a;
        }
        float ps[4][4], pd[4][4];
        #pragma unroll
        for (int reg = 0; reg < 4; ++reg)
            #pragma unroll
            for (int h = 0; h < 4; ++h) {
                ps[reg][h] = acc[2*h][reg] * Asv[2*h] + acc[2*h+1][reg] * Asv[2*h+1];
                pd[reg][h] = acc[2*h][reg] * Adv[2*h] + acc[2*h+1][reg] * Adv[2*h+1];
            }
        #pragma unroll
        for (int m = 1; m <= 8; m <<= 1)
            #pragma unroll
            for (int reg = 0; reg < 4; ++reg)
                #pragma unroll
                for (int h = 0; h < 4; ++h) {
                    ps[reg][h] += __shfl_xor(ps[reg][h], m);
                    pd[reg][h] += __shfl_xor(pd[reg][h], m);
                }
        int rbase = row0 + wv_ * 16 + (lane >> 4) * 4;
        #pragma unroll
        for (int reg = 0; reg < 4; ++reg) {
            int grow = rbase + reg;
            if (grow < nrows) {
                #pragma unroll
                for (int nt = 0; nt < 8; ++nt)
                    H16[(size_t)grow * 128 + nt * 16 + col16] = __float2half(acc[nt][reg]);
                if (col16 == 0) {
                    *reinterpret_cast<float4*>(as_out + (size_t)grow * 4) =
                        make_float4(ps[reg][0], ps[reg][1], ps[reg][2], ps[reg][3]);
                    *reinterpret_cast<float4*>(ad_out + (size_t)grow * 4) =
                        make_float4(pd[reg][0], pd[reg][1], pd[reg][2], pd[reg][3]);
                }
            }
        }
    }
}

// ---- phase B: within-bucket counting sort; emits off_start/off_end --------
__global__ __launch_bounds__(1024) void bucket_sort(const int* __restrict__ bucketed,
                                                    const int* __restrict__ bcursor,
                                                    int* __restrict__ sorted_packed,
                                                    int* __restrict__ off_s,
                                                    int* __restrict__ off_e) {
    __shared__ int cnt[256], scn[256], cur[256];
    int t = threadIdx.x, k = blockIdx.x;
    int base = k * CAP;
    int m = bcursor[k];           // bucket count (scatter cursors hold totals)
    if (t < 256) cnt[t] = 0;
    __syncthreads();
    for (int i = t; i < m; i += 1024)
        atomicAdd(&cnt[bucketed[base + i] & 255], 1);
    __syncthreads();
    if (t < 256) scn[t] = cnt[t];
    __syncthreads();
    for (int o = 1; o < 256; o <<= 1) {
        int v = (t < 256 && t >= o) ? scn[t - o] : 0;
        __syncthreads();
        if (t < 256) scn[t] += v;
        __syncthreads();
    }
    if (t < 256) {
        int excl = scn[t] - cnt[t];
        cur[t] = base + excl;
        int node = k * 256 + t;
        if (node < N_NODES) {
            off_s[node] = base + excl;
            off_e[node] = base + excl + cnt[t];
        }
    }
    __syncthreads();
    for (int i = t; i < m; i += 1024) {
        int rec = bucketed[base + i];
        int p = atomicAdd(&cur[rec & 255], 1);
        sorted_packed[p] = rec;
    }
}

// ---- fused weights + aggregate (round-8 v3 structure) ---------------------
__global__ __launch_bounds__(256) void gat_aggregate_v3(const __half* __restrict__ H16,
                                                        const int* __restrict__ off_s,
                                                        const int* __restrict__ off_e,
                                                        const int* __restrict__ packed,
                                                        const float* __restrict__ asb,
                                                        const float* __restrict__ adb,
                                                        const float* __restrict__ bias,
                                                        float* __restrict__ OUTF,
                                                        __half* __restrict__ OUTH,
                                                        int n, int mode) {
    int wid = (blockIdx.x * 256 + threadIdx.x) >> 6;
    int lane = threadIdx.x & 63;
    if (wid >= n) return;
    int s = off_s[wid], e = off_e[wid];
    int q = lane >> 4;            // edge slot within the 4-group
    int sub = lane & 15;          // 16B chunk of the 256B row
    int head4 = (sub >> 2) * 4;   // byte offset of this head's score
    int sub16 = sub * 16;
    float adv = adb[(size_t)wid * 4 + (sub >> 2)];
    const char* Hc = reinterpret_cast<const char*>(H16);
    const char* Ac = reinterpret_cast<const char*>(asb);
    float acc[8] = {0, 0, 0, 0, 0, 0, 0, 0};
    float den = 0.f;
    if (s < e) {
        int idx[4]; float sc[4];
        #pragma unroll
        for (int u = 0; u < 4; ++u) {
            int ii = s + q + u * 4;
            int jj = ii < e ? ii : s;
            idx[u] = packed[jj] & 0xFFFFFF00;      // src*256 = H row byte offset
            sc[u] = *reinterpret_cast<const float*>(Ac + (idx[u] >> 4) + head4);
        }
        for (int i = s; i < e; i += 16) {
            uint4 h0 = *reinterpret_cast<const uint4*>(Hc + idx[0] + sub16);
            uint4 h1 = *reinterpret_cast<const uint4*>(Hc + idx[1] + sub16);
            uint4 h2 = *reinterpret_cast<const uint4*>(Hc + idx[2] + sub16);
            uint4 h3 = *reinterpret_cast<const uint4*>(Hc + idx[3] + sub16);
            float w[4];
            #pragma unroll
            for (int u = 0; u < 4; ++u) {
                float ev = sc[u] + adv; ev = fmaxf(ev, 0.2f * ev);
                w[u] = (i + q + u * 4 < e) ? __expf(ev) : 0.f;
            }
            #pragma unroll
            for (int u = 0; u < 4; ++u) {          // prefetch next 4 slots
                int ii = i + 16 + q + u * 4;
                int jj = ii < e ? ii : s;
                idx[u] = packed[jj] & 0xFFFFFF00;
                sc[u] = *reinterpret_cast<const float*>(Ac + (idx[u] >> 4) + head4);
            }
            den += (w[0] + w[1]) + (w[2] + w[3]);
#if HAS_FDOT2
            half2_t w01 = __builtin_bit_cast(half2_t, __builtin_amdgcn_cvt_pkrtz(w[0], w[1]));
            half2_t w23 = __builtin_bit_cast(half2_t, __builtin_amdgcn_cvt_pkrtz(w[2], w[3]));
            const uint* a0 = reinterpret_cast<const uint*>(&h0);
            const uint* a1 = reinterpret_cast<const uint*>(&h1);
            const uint* a2 = reinterpret_cast<const uint*>(&h2);
            const uint* a3 = reinterpret_cast<const uint*>(&h3);
            #pragma unroll
            for (int j = 0; j < 4; ++j) {
                uint p0 = __builtin_amdgcn_perm(a1[j], a0[j], 0x05040100u);
                uint p1 = __builtin_amdgcn_perm(a1[j], a0[j], 0x07060302u);
                uint r0 = __builtin_amdgcn_perm(a3[j], a2[j], 0x05040100u);
                uint r1 = __builtin_amdgcn_perm(a3[j], a2[j], 0x07060302u);
                acc[2*j]   = __builtin_amdgcn_fdot2(__builtin_bit_cast(half2_t, p0), w01,
                             __builtin_amdgcn_fdot2(__builtin_bit_cast(half2_t, r0), w23, acc[2*j],   false), false);
                acc[2*j+1] = __builtin_amdgcn_fdot2(__builtin_bit_cast(half2_t, p1), w01,
                             __builtin_amdgcn_fdot2(__builtin_bit_cast(half2_t, r1), w23, acc[2*j+1], false), false);
            }
#else
            const __half2* pa = reinterpret_cast<const __half2*>(&h0);
            const __half2* pb = reinterpret_cast<const __half2*>(&h1);
            const __half2* pc = reinterpret_cast<const __half2*>(&h2);
            const __half2* pd_ = reinterpret_cast<const __half2*>(&h3);
            #pragma unroll
            for (int j = 0; j < 4; ++j) {
                float2 fa = __half22float2(pa[j]);
                float2 fb = __half22float2(pb[j]);
                float2 fc = __half22float2(pc[j]);
                float2 fd = __half22float2(pd_[j]);
                acc[2*j]   += w[0] * fa.x + w[1] * fb.x + w[2] * fc.x + w[3] * fd.x;
                acc[2*j+1] += w[0] * fa.y + w[1] * fb.y + w[2] * fc.y + w[3] * fd.y;
            }
#endif
        }
    }
    #pragma unroll
    for (int j = 0; j < 8; ++j) acc[j] += __shfl_xor(acc[j], 16);
    den += __shfl_xor(den, 16);
    #pragma unroll
    for (int j = 0; j < 8; ++j) acc[j] += __shfl_xor(acc[j], 32);
    den += __shfl_xor(den, 32);
    if (q == 0) {
        float inv = den > 0.f ? 1.f / den : 0.f;
        float4 b0 = *reinterpret_cast<const float4*>(bias + sub * 8);
        float4 b1 = *reinterpret_cast<const float4*>(bias + sub * 8 + 4);
        float o[8];
        o[0] = acc[0]*inv + b0.x; o[1] = acc[1]*inv + b0.y;
        o[2] = acc[2]*inv + b0.z; o[3] = acc[3]*inv + b0.w;
        o[4] = acc[4]*inv + b1.x; o[5] = acc[5]*inv + b1.y;
        o[6] = acc[6]*inv + b1.z; o[7] = acc[7]*inv + b1.w;
        if (mode) {
            uint4 u;
            __half2* up = reinterpret_cast<__half2*>(&u);
            #pragma unroll
            for (int j = 0; j < 4; ++j)
                up[j] = __floats2half2_rn(fmaxf(o[2*j], 0.f), fmaxf(o[2*j+1], 0.f));
            *reinterpret_cast<uint4*>(OUTH + (size_t)wid * 128 + sub * 8) = u;
        } else {
            *reinterpret_cast<float4*>(OUTF + (size_t)wid * 128 + sub * 8) =
                make_float4(o[0], o[1], o[2], o[3]);
            *reinterpret_cast<float4*>(OUTF + (size_t)wid * 128 + sub * 8 + 4) =
                make_float4(o[4], o[5], o[6], o[7]);
        }
    }
}

// ---------------------------------------------------------------------------
extern "C" void kernel_launch(void* const* d_in, const int* in_sizes, int n_in,
                              void* d_out, int out_size, void* d_ws, size_t ws_size,
                              hipStream_t stream) {
    const float* x        = (const float*)d_in[0];
    const int*   edge     = (const int*)d_in[1];
    const float* W0       = (const float*)d_in[2];
    const float* att_src0 = (const float*)d_in[3];
    const float* att_dst0 = (const float*)d_in[4];
    const float* b0       = (const float*)d_in[5];
    const float* W1       = (const float*)d_in[6];
    const float* att_src1 = (const float*)d_in[7];
    const float* att_dst1 = (const float*)d_in[8];
    const float* b1       = (const float*)d_in[9];
    const int* src = edge;
    const int* dst = edge + N_EDGES;
    float* out = (float*)d_out;

    char* ws = (char*)d_ws;
    size_t o = 0;
    auto alloc = [&](size_t bytes) { char* p = ws + o; o += (bytes + 255) & ~(size_t)255; return p; };
    __half* H16   = (__half*)alloc((size_t)N_NODES * 128 * 2);    // 12.8 MB (persistent)
    float* asb    = (float*)alloc((size_t)N_NODES * 4 * 4);
    float* adb    = (float*)alloc((size_t)N_NODES * 4 * 4);
    int*   off_s  = (int*)alloc((size_t)N_NODES * 4);
    int*   off_e  = (int*)alloc((size_t)N_NODES * 4);
    int*   sorted = (int*)alloc((size_t)NB * CAP * 4);            // 7.0 MB (persistent)
    // overlay: sort temps, later reused as the f16 layer-0 output
    size_t mark = o;
    int*   bcursor  = (int*)alloc((size_t)NB * 4);                // 784 B
    int*   bucketed = (int*)alloc((size_t)NB * CAP * 4);          // 7.0 MB
    o = mark + (size_t)N_NODES * 128 * 2;                         // reserve h1 region
    __half* h1_16 = (__half*)(ws + mark);                         // 12.8 MB, aliases temps

    // ---- zero bucket cursors (784 B), then layer-0 GEMM ∥ bucket scatter ----
    hipMemsetAsync(bcursor, 0, (size_t)NB * 4, stream);
    gemm_mfma<<<GEMM_BLOCKS + NBLK_S, 256, 0, stream>>>(x, (const __half*)nullptr, 0,
                                                        W0, att_src0, att_dst0,
                                                        H16, asb, adb, N_NODES,
                                                        src, dst, bcursor, bucketed, 1);
    // ---- within-bucket sort (emits off_start/off_end) ----
    bucket_sort<<<NB, 1024, 0, stream>>>(bucketed, bcursor, sorted, off_s, off_e);

    int agg_blocks = N_NODES / 4;   // 12500, exact

    // ---- layer 0 aggregate (writes f16 + relu) ----
    gat_aggregate_v3<<<agg_blocks, 256, 0, stream>>>(H16, off_s, off_e, sorted, asb, adb, b0,
                                                     (float*)nullptr, h1_16, N_NODES, 1);

    // ---- layer 1 ----
    gemm_mfma<<<GEMM_BLOCKS, 256, 0, stream>>>((const float*)nullptr, h1_16, 1,
                                               W1, att_src1, att_dst1,
                                               H16, asb, adb, N_NODES,
                                               (const int*)nullptr, (const int*)nullptr,
                                               (int*)nullptr, (int*)nullptr, 0);
    gat_aggregate_v3<<<agg_blocks, 256, 0, stream>>>(H16, off_s, off_e, sorted, asb, adb, b1,
                                                     out, (__half*)nullptr, N_NODES, 0);
}

// Round 12
// 184.366 us; speedup vs baseline: 1.7807x; 1.0290x over previous
//
#include <hip/hip_runtime.h>
#include <hip/hip_fp16.h>

#define N_NODES 50000
#define N_EDGES 1600000
#define NB 196                    // buckets: dst>>8
#define CAP 8960                  // fixed per-bucket capacity (mean 8163 + 8.8 sigma)
#define NBLK_S 512                // scatter blocks
#define CHUNK_S (N_EDGES / NBLK_S)   // 3125
#define GEMM0_BLOCKS 256          // gemm blocks in the fused gemm0||scatter dispatch
#define GEMM1_BLOCKS 768          // standalone gemm1 blocks (1 tile each, 3/CU)

typedef _Float16 half8_t __attribute__((ext_vector_type(8)));
typedef _Float16 half2_t __attribute__((ext_vector_type(2)));
typedef float floatx4 __attribute__((ext_vector_type(4)));

#if defined(__has_builtin)
#  if __has_builtin(__builtin_amdgcn_fdot2)
#    define HAS_FDOT2 1
#  endif
#endif
#ifndef HAS_FDOT2
#  define HAS_FDOT2 0
#endif

// ---- prep: build swizzled-f16 W images (exact LDS layout) + zero cursors --
__global__ __launch_bounds__(256) void prep(const float* __restrict__ W0,
                                            const float* __restrict__ W1,
                                            __half* __restrict__ img0,
                                            __half* __restrict__ img1,
                                            int* __restrict__ bcursor) {
    int t = threadIdx.x, b = blockIdx.x;
    const float* W = b ? W1 : W0;
    char* img = reinterpret_cast<char*>(b ? img1 : img0);
    int n = t & 127;
    int k0 = (t >> 7) * 64;      // two k-halves per n
    for (int kk = 0; kk < 64; ++kk) {
        int k = k0 + kk;
        float v = W[(size_t)k * 128 + n];   // coalesced across lanes at fixed k
        int byte = (n * 256 + k * 2) ^ ((n & 7) << 4);
        *reinterpret_cast<__half*>(img + byte) = __float2half(v);
    }
    if (b == 0 && t < NB) bcursor[t] = 0;
}

// ---- MFMA f16 GEMM (persistent) + score epilogue, ∥ bucket scatter --------
__global__ __launch_bounds__(256) void gemm_mfma(const float* __restrict__ Xf,
                                                 const __half* __restrict__ Xh,
                                                 int in_half,
                                                 const __half* __restrict__ Wimg,
                                                 const float* __restrict__ att_s,
                                                 const float* __restrict__ att_d,
                                                 __half* __restrict__ H16,
                                                 float* __restrict__ as_out,
                                                 float* __restrict__ ad_out, int nrows,
                                                 int ngemm,
                                                 const int* __restrict__ e_src,
                                                 const int* __restrict__ e_dst,
                                                 int* __restrict__ bcursor,
                                                 int* __restrict__ bucketed,
                                                 int with_scatter) {
    __shared__ __align__(16) char lds[49152];   // GEMM: A[0,16K) Wt[16K,48K)
    int t = threadIdx.x;
    // ---- scatter role: LDS-reorder + coalesced fixed-stride run writes ----
    if (with_scatter && blockIdx.x >= ngemm) {
        int* recs   = reinterpret_cast<int*>(lds);            // 3125 ints
        int* srt    = reinterpret_cast<int*>(lds + 12800);    // 3125 ints
        int* hist   = reinterpret_cast<int*>(lds + 25600);    // NB
        int* lstart = reinterpret_cast<int*>(lds + 26624);    // NB
        int* curL   = reinterpret_cast<int*>(lds + 27648);    // NB
        int* gbase  = reinterpret_cast<int*>(lds + 28672);    // NB
        int b = blockIdx.x - ngemm;
        if (t < NB) hist[t] = 0;
        __syncthreads();
        int s0 = b * CHUNK_S;
        for (int i = t; i < CHUNK_S; i += 256) {
            unsigned sv = (unsigned)e_src[s0 + i], dv = (unsigned)e_dst[s0 + i];
            recs[i] = (int)((sv << 16) | dv);
            atomicAdd(&hist[dv >> 8], 1);
        }
        __syncthreads();
        int myCnt = (t < NB) ? hist[t] : 0;
        if (t < NB) lstart[t] = myCnt;
        __syncthreads();
        for (int o = 1; o < NB; o <<= 1) {       // scan of block-local hist
            int v = (t < NB && t >= o) ? lstart[t - o] : 0;
            __syncthreads();
            if (t < NB) lstart[t] += v;
            __syncthreads();
        }
        if (t < NB) {
            int ex = lstart[t] - myCnt;
            lstart[t] = ex;
            curL[t] = ex;
            gbase[t] = t * CAP + atomicAdd(&bcursor[t], myCnt);  // claim run
        }
        __syncthreads();
        for (int i = t; i < CHUNK_S; i += 256) { // LDS reorder by bucket
            int r = recs[i];
            int bk = (int)(((unsigned)r & 0xFFFFu) >> 8);
            int p = atomicAdd(&curL[bk], 1);
            srt[p] = r;
        }
        __syncthreads();
        for (int p = t; p < CHUNK_S; p += 256) { // coalesced run writes
            int r = srt[p];
            unsigned d = (unsigned)r & 0xFFFFu;
            int bk = (int)(d >> 8);
            int g = gbase[bk] + (p - lstart[bk]);
            bucketed[g] = (int)((((unsigned)r >> 16) << 8) | (d & 255u));
        }
        return;
    }
    // ---- GEMM role ----
    char* Alds = lds;
    char* Wlds = lds + 16384;
    int lane = t & 63, wv_ = t >> 6;
    {   // stage Wt image (pre-swizzled in global) -> vectorized 32KB copy
        const uint4* wi = reinterpret_cast<const uint4*>(Wimg);
        uint4* wl = reinterpret_cast<uint4*>(Wlds);
        #pragma unroll
        for (int p = 0; p < 8; ++p) wl[p * 256 + t] = wi[p * 256 + t];
    }
    int col16 = lane & 15;
    float Asv[8], Adv[8];
    #pragma unroll
    for (int nt = 0; nt < 8; ++nt) {
        Asv[nt] = att_s[nt * 16 + col16];
        Adv[nt] = att_d[nt * 16 + col16];
    }
    int ksub = (lane >> 4) * 16;
    int rloc = wv_ * 16 + col16;
    int ntiles = (nrows + 63) / 64;
    for (int tile = blockIdx.x; tile < ntiles; tile += ngemm) {
        int row0 = tile * 64;
        __syncthreads();
        for (int p = 0; p < 8; ++p) {
            int r = p * 8 + (t >> 5);
            int f4 = t & 31;
            int rr = row0 + r;
            uint2 hv = make_uint2(0, 0);
            if (rr < nrows) {
                if (in_half) {
                    hv = *reinterpret_cast<const uint2*>(Xh + (size_t)rr * 128 + f4 * 4);
                } else {
                    float4 xv = reinterpret_cast<const float4*>(Xf)[(size_t)rr * 32 + f4];
                    __half2* hp = reinterpret_cast<__half2*>(&hv);
                    hp[0] = __floats2half2_rn(xv.x, xv.y);
                    hp[1] = __floats2half2_rn(xv.z, xv.w);
                }
            }
            int byte = (r * 256 + f4 * 8) ^ ((r & 7) << 4);
            *reinterpret_cast<uint2*>(Alds + byte) = hv;
        }
        __syncthreads();
        half8_t afr[4];
        #pragma unroll
        for (int kb = 0; kb < 4; ++kb) {
            int byte = (rloc * 256 + kb * 64 + ksub) ^ ((rloc & 7) << 4);
            afr[kb] = *reinterpret_cast<half8_t*>(Alds + byte);
        }
        floatx4 acc[8];
        #pragma unroll
        for (int nt = 0; nt < 8; ++nt) {
            int n = nt * 16 + col16;
            floatx4 a = {0.f, 0.f, 0.f, 0.f};
            #pragma unroll
            for (int kb = 0; kb < 4; ++kb) {
                int byte = (n * 256 + kb * 64 + ksub) ^ ((n & 7) << 4);
                half8_t bfr = *reinterpret_cast<half8_t*>(Wlds + byte);
                a = __builtin_amdgcn_mfma_f32_16x16x32_f16(afr[kb], bfr, a, 0, 0, 0);
            }
            acc[nt] = a;
        }
        float ps[4][4], pd[4][4];
        #pragma unroll
        for (int reg = 0; reg < 4; ++reg)
            #pragma unroll
            for (int h = 0; h < 4; ++h) {
                ps[reg][h] = acc[2*h][reg] * Asv[2*h] + acc[2*h+1][reg] * Asv[2*h+1];
                pd[reg][h] = acc[2*h][reg] * Adv[2*h] + acc[2*h+1][reg] * Adv[2*h+1];
            }
        #pragma unroll
        for (int m = 1; m <= 8; m <<= 1)
            #pragma unroll
            for (int reg = 0; reg < 4; ++reg)
                #pragma unroll
                for (int h = 0; h < 4; ++h) {
                    ps[reg][h] += __shfl_xor(ps[reg][h], m);
                    pd[reg][h] += __shfl_xor(pd[reg][h], m);
                }
        int rbase = row0 + wv_ * 16 + (lane >> 4) * 4;
        #pragma unroll
        for (int reg = 0; reg < 4; ++reg) {
            int grow = rbase + reg;
            if (grow < nrows) {
                #pragma unroll
                for (int nt = 0; nt < 8; ++nt)
                    H16[(size_t)grow * 128 + nt * 16 + col16] = __float2half(acc[nt][reg]);
                if (col16 == 0) {
                    *reinterpret_cast<float4*>(as_out + (size_t)grow * 4) =
                        make_float4(ps[reg][0], ps[reg][1], ps[reg][2], ps[reg][3]);
                    *reinterpret_cast<float4*>(ad_out + (size_t)grow * 4) =
                        make_float4(pd[reg][0], pd[reg][1], pd[reg][2], pd[reg][3]);
                }
            }
        }
    }
}

// ---- phase B: within-bucket counting sort (records staged in LDS once) ----
__global__ __launch_bounds__(1024) void bucket_sort(const int* __restrict__ bucketed,
                                                    const int* __restrict__ bcursor,
                                                    int* __restrict__ sorted_packed,
                                                    int* __restrict__ off_s,
                                                    int* __restrict__ off_e) {
    __shared__ int recs[CAP];
    __shared__ int cnt[256], scn[256], cur[256];
    int t = threadIdx.x, k = blockIdx.x;
    int base = k * CAP;
    int m = bcursor[k];           // bucket count (scatter cursors hold totals)
    if (t < 256) cnt[t] = 0;
    __syncthreads();
    for (int i = t; i < m; i += 1024) {
        int r = bucketed[base + i];
        recs[i] = r;
        atomicAdd(&cnt[r & 255], 1);
    }
    __syncthreads();
    if (t < 256) scn[t] = cnt[t];
    __syncthreads();
    for (int o = 1; o < 256; o <<= 1) {
        int v = (t < 256 && t >= o) ? scn[t - o] : 0;
        __syncthreads();
        if (t < 256) scn[t] += v;
        __syncthreads();
    }
    if (t < 256) {
        int excl = scn[t] - cnt[t];
        cur[t] = base + excl;
        int node = k * 256 + t;
        if (node < N_NODES) {
            off_s[node] = base + excl;
            off_e[node] = base + excl + cnt[t];
        }
    }
    __syncthreads();
    for (int i = t; i < m; i += 1024) {
        int rec = recs[i];
        int p = atomicAdd(&cur[rec & 255], 1);
        sorted_packed[p] = rec;
    }
}

// ---- fused weights + aggregate (round-8 v3 structure, unchanged) ----------
__global__ __launch_bounds__(256) void gat_aggregate_v3(const __half* __restrict__ H16,
                                                        const int* __restrict__ off_s,
                                                        const int* __restrict__ off_e,
                                                        const int* __restrict__ packed,
                                                        const float* __restrict__ asb,
                                                        const float* __restrict__ adb,
                                                        const float* __restrict__ bias,
                                                        float* __restrict__ OUTF,
                                                        __half* __restrict__ OUTH,
                                                        int n, int mode) {
    int wid = (blockIdx.x * 256 + threadIdx.x) >> 6;
    int lane = threadIdx.x & 63;
    if (wid >= n) return;
    int s = off_s[wid], e = off_e[wid];
    int q = lane >> 4;            // edge slot within the 4-group
    int sub = lane & 15;          // 16B chunk of the 256B row
    int head4 = (sub >> 2) * 4;   // byte offset of this head's score
    int sub16 = sub * 16;
    float adv = adb[(size_t)wid * 4 + (sub >> 2)];
    const char* Hc = reinterpret_cast<const char*>(H16);
    const char* Ac = reinterpret_cast<const char*>(asb);
    float acc[8] = {0, 0, 0, 0, 0, 0, 0, 0};
    float den = 0.f;
    if (s < e) {
        int idx[4]; float sc[4];
        #pragma unroll
        for (int u = 0; u < 4; ++u) {
            int ii = s + q + u * 4;
            int jj = ii < e ? ii : s;
            idx[u] = packed[jj] & 0xFFFFFF00;      // src*256 = H row byte offset
            sc[u] = *reinterpret_cast<const float*>(Ac + (idx[u] >> 4) + head4);
        }
        for (int i = s; i < e; i += 16) {
            uint4 h0 = *reinterpret_cast<const uint4*>(Hc + idx[0] + sub16);
            uint4 h1 = *reinterpret_cast<const uint4*>(Hc + idx[1] + sub16);
            uint4 h2 = *reinterpret_cast<const uint4*>(Hc + idx[2] + sub16);
            uint4 h3 = *reinterpret_cast<const uint4*>(Hc + idx[3] + sub16);
            float w[4];
            #pragma unroll
            for (int u = 0; u < 4; ++u) {
                float ev = sc[u] + adv; ev = fmaxf(ev, 0.2f * ev);
                w[u] = (i + q + u * 4 < e) ? __expf(ev) : 0.f;
            }
            #pragma unroll
            for (int u = 0; u < 4; ++u) {          // prefetch next 4 slots
                int ii = i + 16 + q + u * 4;
                int jj = ii < e ? ii : s;
                idx[u] = packed[jj] & 0xFFFFFF00;
                sc[u] = *reinterpret_cast<const float*>(Ac + (idx[u] >> 4) + head4);
            }
            den += (w[0] + w[1]) + (w[2] + w[3]);
#if HAS_FDOT2
            half2_t w01 = __builtin_bit_cast(half2_t, __builtin_amdgcn_cvt_pkrtz(w[0], w[1]));
            half2_t w23 = __builtin_bit_cast(half2_t, __builtin_amdgcn_cvt_pkrtz(w[2], w[3]));
            const uint* a0 = reinterpret_cast<const uint*>(&h0);
            const uint* a1 = reinterpret_cast<const uint*>(&h1);
            const uint* a2 = reinterpret_cast<const uint*>(&h2);
            const uint* a3 = reinterpret_cast<const uint*>(&h3);
            #pragma unroll
            for (int j = 0; j < 4; ++j) {
                uint p0 = __builtin_amdgcn_perm(a1[j], a0[j], 0x05040100u);
                uint p1 = __builtin_amdgcn_perm(a1[j], a0[j], 0x07060302u);
                uint r0 = __builtin_amdgcn_perm(a3[j], a2[j], 0x05040100u);
                uint r1 = __builtin_amdgcn_perm(a3[j], a2[j], 0x07060302u);
                acc[2*j]   = __builtin_amdgcn_fdot2(__builtin_bit_cast(half2_t, p0), w01,
                             __builtin_amdgcn_fdot2(__builtin_bit_cast(half2_t, r0), w23, acc[2*j],   false), false);
                acc[2*j+1] = __builtin_amdgcn_fdot2(__builtin_bit_cast(half2_t, p1), w01,
                             __builtin_amdgcn_fdot2(__builtin_bit_cast(half2_t, r1), w23, acc[2*j+1], false), false);
            }
#else
            const __half2* pa = reinterpret_cast<const __half2*>(&h0);
            const __half2* pb = reinterpret_cast<const __half2*>(&h1);
            const __half2* pc = reinterpret_cast<const __half2*>(&h2);
            const __half2* pd_ = reinterpret_cast<const __half2*>(&h3);
            #pragma unroll
            for (int j = 0; j < 4; ++j) {
                float2 fa = __half22float2(pa[j]);
                float2 fb = __half22float2(pb[j]);
                float2 fc = __half22float2(pc[j]);
                float2 fd = __half22float2(pd_[j]);
                acc[2*j]   += w[0] * fa.x + w[1] * fb.x + w[2] * fc.x + w[3] * fd.x;
                acc[2*j+1] += w[0] * fa.y + w[1] * fb.y + w[2] * fc.y + w[3] * fd.y;
            }
#endif
        }
    }
    #pragma unroll
    for (int j = 0; j < 8; ++j) acc[j] += __shfl_xor(acc[j], 16);
    den += __shfl_xor(den, 16);
    #pragma unroll
    for (int j = 0; j < 8; ++j) acc[j] += __shfl_xor(acc[j], 32);
    den += __shfl_xor(den, 32);
    if (q == 0) {
        float inv = den > 0.f ? 1.f / den : 0.f;
        float4 b0 = *reinterpret_cast<const float4*>(bias + sub * 8);
        float4 b1 = *reinterpret_cast<const float4*>(bias + sub * 8 + 4);
        float o[8];
        o[0] = acc[0]*inv + b0.x; o[1] = acc[1]*inv + b0.y;
        o[2] = acc[2]*inv + b0.z; o[3] = acc[3]*inv + b0.w;
        o[4] = acc[4]*inv + b1.x; o[5] = acc[5]*inv + b1.y;
        o[6] = acc[6]*inv + b1.z; o[7] = acc[7]*inv + b1.w;
        if (mode) {
            uint4 u;
            __half2* up = reinterpret_cast<__half2*>(&u);
            #pragma unroll
            for (int j = 0; j < 4; ++j)
                up[j] = __floats2half2_rn(fmaxf(o[2*j], 0.f), fmaxf(o[2*j+1], 0.f));
            *reinterpret_cast<uint4*>(OUTH + (size_t)wid * 128 + sub * 8) = u;
        } else {
            *reinterpret_cast<float4*>(OUTF + (size_t)wid * 128 + sub * 8) =
                make_float4(o[0], o[1], o[2], o[3]);
            *reinterpret_cast<float4*>(OUTF + (size_t)wid * 128 + sub * 8 + 4) =
                make_float4(o[4], o[5], o[6], o[7]);
        }
    }
}

// ---------------------------------------------------------------------------
extern "C" void kernel_launch(void* const* d_in, const int* in_sizes, int n_in,
                              void* d_out, int out_size, void* d_ws, size_t ws_size,
                              hipStream_t stream) {
    const float* x        = (const float*)d_in[0];
    const int*   edge     = (const int*)d_in[1];
    const float* W0       = (const float*)d_in[2];
    const float* att_src0 = (const float*)d_in[3];
    const float* att_dst0 = (const float*)d_in[4];
    const float* b0       = (const float*)d_in[5];
    const float* W1       = (const float*)d_in[6];
    const float* att_src1 = (const float*)d_in[7];
    const float* att_dst1 = (const float*)d_in[8];
    const float* b1       = (const float*)d_in[9];
    const int* src = edge;
    const int* dst = edge + N_EDGES;
    float* out = (float*)d_out;

    char* ws = (char*)d_ws;
    size_t o = 0;
    auto alloc = [&](size_t bytes) { char* p = ws + o; o += (bytes + 255) & ~(size_t)255; return p; };
    __half* H16   = (__half*)alloc((size_t)N_NODES * 128 * 2);    // 12.8 MB (persistent)
    float* asb    = (float*)alloc((size_t)N_NODES * 4 * 4);
    float* adb    = (float*)alloc((size_t)N_NODES * 4 * 4);
    int*   off_s  = (int*)alloc((size_t)N_NODES * 4);
    int*   off_e  = (int*)alloc((size_t)N_NODES * 4);
    int*   sorted = (int*)alloc((size_t)NB * CAP * 4);            // 7.0 MB (persistent)
    __half* img0  = (__half*)alloc(32768);                        // swizzled W0 f16 image
    __half* img1  = (__half*)alloc(32768);                        // swizzled W1 f16 image
    // overlay: sort temps, later reused as the f16 layer-0 output
    size_t mark = o;
    int*   bcursor  = (int*)alloc((size_t)NB * 4);                // 784 B
    int*   bucketed = (int*)alloc((size_t)NB * CAP * 4);          // 7.0 MB
    o = mark + (size_t)N_NODES * 128 * 2;                         // reserve h1 region
    __half* h1_16 = (__half*)(ws + mark);                         // 12.8 MB, aliases temps

    // ---- prep: W images + cursor zeroing (replaces memset) ----
    prep<<<2, 256, 0, stream>>>(W0, W1, img0, img1, bcursor);

    // ---- layer-0 GEMM ∥ bucket scatter ----
    gemm_mfma<<<GEMM0_BLOCKS + NBLK_S, 256, 0, stream>>>(x, (const __half*)nullptr, 0,
                                                         img0, att_src0, att_dst0,
                                                         H16, asb, adb, N_NODES, GEMM0_BLOCKS,
                                                         src, dst, bcursor, bucketed, 1);
    // ---- within-bucket sort (emits off_start/off_end) ----
    bucket_sort<<<NB, 1024, 0, stream>>>(bucketed, bcursor, sorted, off_s, off_e);

    int agg_blocks = N_NODES / 4;   // 12500, exact

    // ---- layer 0 aggregate (writes f16 + relu) ----
    gat_aggregate_v3<<<agg_blocks, 256, 0, stream>>>(H16, off_s, off_e, sorted, asb, adb, b0,
                                                     (float*)nullptr, h1_16, N_NODES, 1);

    // ---- layer 1 ----
    gemm_mfma<<<GEMM1_BLOCKS, 256, 0, stream>>>((const float*)nullptr, h1_16, 1,
                                                img1, att_src1, att_dst1,
                                                H16, asb, adb, N_NODES, GEMM1_BLOCKS,
                                                (const int*)nullptr, (const int*)nullptr,
                                                (int*)nullptr, (int*)nullptr, 0);
    gat_aggregate_v3<<<agg_blocks, 256, 0, stream>>>(H16, off_s, off_e, sorted, asb, adb, b1,
                                                     out, (__half*)nullptr, N_NODES, 0);
}

// Round 13
// 178.976 us; speedup vs baseline: 1.8344x; 1.0301x over previous
//
#include <hip/hip_runtime.h>
#include <hip/hip_fp16.h>

#define N_NODES 50000
#define N_EDGES 1600000
#define NB 196                    // buckets: dst>>8
#define CAP 8960                  // fixed per-bucket capacity (mean 8163 + 8.8 sigma)
#define NBLK_S 400                // scatter blocks in the fused dispatch
#define CHUNK_S (N_EDGES / NBLK_S)   // 4000 exactly
#define GEMM0_BLOCKS 368          // gemm blocks in the fused gemm0||scatter dispatch
#define GEMM1_BLOCKS 782          // standalone gemm1: exactly 1 tile per block

typedef _Float16 half8_t __attribute__((ext_vector_type(8)));
typedef _Float16 half2_t __attribute__((ext_vector_type(2)));
typedef float floatx4 __attribute__((ext_vector_type(4)));

#if defined(__has_builtin)
#  if __has_builtin(__builtin_amdgcn_fdot2)
#    define HAS_FDOT2 1
#  endif
#endif
#ifndef HAS_FDOT2
#  define HAS_FDOT2 0
#endif

// ---- prep: build swizzled-f16 W images (vectorized) + zero cursors --------
__global__ __launch_bounds__(256) void prep(const float* __restrict__ W0,
                                            const float* __restrict__ W1,
                                            __half* __restrict__ img0,
                                            __half* __restrict__ img1,
                                            int* __restrict__ bcursor) {
    int t = threadIdx.x, b = blockIdx.x;
    const float* W = b ? W1 : W0;
    char* img = reinterpret_cast<char*>(b ? img1 : img0);
    // 2048 16B granules; granule g = (n, kk): bytes [kk*16, kk*16+16) of row n
    #pragma unroll
    for (int i = 0; i < 8; ++i) {
        int g = i * 256 + t;
        int n = g >> 4;
        int kk = g & 15;
        uint4 u;
        __half* uh = reinterpret_cast<__half*>(&u);
        #pragma unroll
        for (int j = 0; j < 8; ++j)
            uh[j] = __float2half(W[(size_t)(kk * 8 + j) * 128 + n]);
        int byte = (n * 256 + kk * 16) ^ ((n & 7) << 4);
        *reinterpret_cast<uint4*>(img + byte) = u;
    }
    if (b == 0 && t < NB) bcursor[t] = 0;
}

// ---- MFMA f16 GEMM (persistent) + score epilogue, ∥ bucket scatter --------
__global__ __launch_bounds__(256) void gemm_mfma(const float* __restrict__ Xf,
                                                 const __half* __restrict__ Xh,
                                                 int in_half,
                                                 const __half* __restrict__ Wimg,
                                                 const float* __restrict__ att_s,
                                                 const float* __restrict__ att_d,
                                                 __half* __restrict__ H16,
                                                 float* __restrict__ as_out,
                                                 float* __restrict__ ad_out, int nrows,
                                                 int ngemm,
                                                 const int* __restrict__ e_src,
                                                 const int* __restrict__ e_dst,
                                                 int* __restrict__ bcursor,
                                                 int* __restrict__ bucketed,
                                                 int with_scatter) {
    __shared__ __align__(16) char lds[49152];   // GEMM: A[0,16K) Wt[16K,48K)
    int t = threadIdx.x;
    // ---- scatter role: LDS-reorder + coalesced fixed-stride run writes ----
    if (with_scatter && blockIdx.x >= ngemm) {
        int* recs   = reinterpret_cast<int*>(lds);            // 4000 ints
        int* srt    = reinterpret_cast<int*>(lds + 16000);    // 4000 ints
        int* hist   = reinterpret_cast<int*>(lds + 32000);    // NB
        int* lstart = reinterpret_cast<int*>(lds + 32784);    // NB
        int* curL   = reinterpret_cast<int*>(lds + 33568);    // NB
        int* gbase  = reinterpret_cast<int*>(lds + 34352);    // NB
        int b = blockIdx.x - ngemm;
        if (t < NB) hist[t] = 0;
        __syncthreads();
        int s0 = b * CHUNK_S;
        for (int i = t; i < CHUNK_S; i += 256) {
            unsigned sv = (unsigned)e_src[s0 + i], dv = (unsigned)e_dst[s0 + i];
            recs[i] = (int)((sv << 16) | dv);
            atomicAdd(&hist[dv >> 8], 1);
        }
        __syncthreads();
        int myCnt = (t < NB) ? hist[t] : 0;
        if (t < NB) lstart[t] = myCnt;
        __syncthreads();
        for (int o = 1; o < NB; o <<= 1) {       // scan of block-local hist
            int v = (t < NB && t >= o) ? lstart[t - o] : 0;
            __syncthreads();
            if (t < NB) lstart[t] += v;
            __syncthreads();
        }
        if (t < NB) {
            int ex = lstart[t] - myCnt;
            lstart[t] = ex;
            curL[t] = ex;
            gbase[t] = t * CAP + atomicAdd(&bcursor[t], myCnt);  // claim run
        }
        __syncthreads();
        for (int i = t; i < CHUNK_S; i += 256) { // LDS reorder by bucket
            int r = recs[i];
            int bk = (int)(((unsigned)r & 0xFFFFu) >> 8);
            int p = atomicAdd(&curL[bk], 1);
            srt[p] = r;
        }
        __syncthreads();
        for (int p = t; p < CHUNK_S; p += 256) { // coalesced run writes
            int r = srt[p];
            unsigned d = (unsigned)r & 0xFFFFu;
            int bk = (int)(d >> 8);
            int g = gbase[bk] + (p - lstart[bk]);
            bucketed[g] = (int)((((unsigned)r >> 16) << 8) | (d & 255u));
        }
        return;
    }
    // ---- GEMM role ----
    char* Alds = lds;
    char* Wlds = lds + 16384;
    int lane = t & 63, wv_ = t >> 6;
    {   // stage Wt image (pre-swizzled in global) -> vectorized 32KB copy
        const uint4* wi = reinterpret_cast<const uint4*>(Wimg);
        uint4* wl = reinterpret_cast<uint4*>(Wlds);
        #pragma unroll
        for (int p = 0; p < 8; ++p) wl[p * 256 + t] = wi[p * 256 + t];
    }
    int col16 = lane & 15;
    float Asv[8], Adv[8];
    #pragma unroll
    for (int nt = 0; nt < 8; ++nt) {
        Asv[nt] = att_s[nt * 16 + col16];
        Adv[nt] = att_d[nt * 16 + col16];
    }
    int ksub = (lane >> 4) * 16;
    int rloc = wv_ * 16 + col16;
    int ntiles = (nrows + 63) / 64;
    for (int tile = blockIdx.x; tile < ntiles; tile += ngemm) {
        int row0 = tile * 64;
        __syncthreads();
        for (int p = 0; p < 8; ++p) {
            int r = p * 8 + (t >> 5);
            int f4 = t & 31;
            int rr = row0 + r;
            uint2 hv = make_uint2(0, 0);
            if (rr < nrows) {
                if (in_half) {
                    hv = *reinterpret_cast<const uint2*>(Xh + (size_t)rr * 128 + f4 * 4);
                } else {
                    float4 xv = reinterpret_cast<const float4*>(Xf)[(size_t)rr * 32 + f4];
                    __half2* hp = reinterpret_cast<__half2*>(&hv);
                    hp[0] = __floats2half2_rn(xv.x, xv.y);
                    hp[1] = __floats2half2_rn(xv.z, xv.w);
                }
            }
            int byte = (r * 256 + f4 * 8) ^ ((r & 7) << 4);
            *reinterpret_cast<uint2*>(Alds + byte) = hv;
        }
        __syncthreads();
        half8_t afr[4];
        #pragma unroll
        for (int kb = 0; kb < 4; ++kb) {
            int byte = (rloc * 256 + kb * 64 + ksub) ^ ((rloc & 7) << 4);
            afr[kb] = *reinterpret_cast<half8_t*>(Alds + byte);
        }
        floatx4 acc[8];
        #pragma unroll
        for (int nt = 0; nt < 8; ++nt) {
            int n = nt * 16 + col16;
            floatx4 a = {0.f, 0.f, 0.f, 0.f};
            #pragma unroll
            for (int kb = 0; kb < 4; ++kb) {
                int byte = (n * 256 + kb * 64 + ksub) ^ ((n & 7) << 4);
                half8_t bfr = *reinterpret_cast<half8_t*>(Wlds + byte);
                a = __builtin_amdgcn_mfma_f32_16x16x32_f16(afr[kb], bfr, a, 0, 0, 0);
            }
            acc[nt] = a;
        }
        float ps[4][4], pd[4][4];
        #pragma unroll
        for (int reg = 0; reg < 4; ++reg)
            #pragma unroll
            for (int h = 0; h < 4; ++h) {
                ps[reg][h] = acc[2*h][reg] * Asv[2*h] + acc[2*h+1][reg] * Asv[2*h+1];
                pd[reg][h] = acc[2*h][reg] * Adv[2*h] + acc[2*h+1][reg] * Adv[2*h+1];
            }
        #pragma unroll
        for (int m = 1; m <= 8; m <<= 1)
            #pragma unroll
            for (int reg = 0; reg < 4; ++reg)
                #pragma unroll
                for (int h = 0; h < 4; ++h) {
                    ps[reg][h] += __shfl_xor(ps[reg][h], m);
                    pd[reg][h] += __shfl_xor(pd[reg][h], m);
                }
        int rbase = row0 + wv_ * 16 + (lane >> 4) * 4;
        #pragma unroll
        for (int reg = 0; reg < 4; ++reg) {
            int grow = rbase + reg;
            if (grow < nrows) {
                #pragma unroll
                for (int nt = 0; nt < 8; ++nt)
                    H16[(size_t)grow * 128 + nt * 16 + col16] = __float2half(acc[nt][reg]);
                if (col16 == 0) {
                    *reinterpret_cast<float4*>(as_out + (size_t)grow * 4) =
                        make_float4(ps[reg][0], ps[reg][1], ps[reg][2], ps[reg][3]);
                    *reinterpret_cast<float4*>(ad_out + (size_t)grow * 4) =
                        make_float4(pd[reg][0], pd[reg][1], pd[reg][2], pd[reg][3]);
                }
            }
        }
    }
}

// ---- phase B: within-bucket counting sort (records staged in LDS once) ----
__global__ __launch_bounds__(1024) void bucket_sort(const int* __restrict__ bucketed,
                                                    const int* __restrict__ bcursor,
                                                    int* __restrict__ sorted_packed,
                                                    int* __restrict__ off_s,
                                                    int* __restrict__ off_e) {
    __shared__ int recs[CAP];
    __shared__ int cnt[256], scn[256], cur[256];
    int t = threadIdx.x, k = blockIdx.x;
    int base = k * CAP;
    int m = bcursor[k];           // bucket count (scatter cursors hold totals)
    if (t < 256) cnt[t] = 0;
    __syncthreads();
    for (int i = t; i < m; i += 1024) {
        int r = bucketed[base + i];
        recs[i] = r;
        atomicAdd(&cnt[r & 255], 1);
    }
    __syncthreads();
    if (t < 256) scn[t] = cnt[t];
    __syncthreads();
    for (int o = 1; o < 256; o <<= 1) {
        int v = (t < 256 && t >= o) ? scn[t - o] : 0;
        __syncthreads();
        if (t < 256) scn[t] += v;
        __syncthreads();
    }
    if (t < 256) {
        int excl = scn[t] - cnt[t];
        cur[t] = base + excl;
        int node = k * 256 + t;
        if (node < N_NODES) {
            off_s[node] = base + excl;
            off_e[node] = base + excl + cnt[t];
        }
    }
    __syncthreads();
    for (int i = t; i < m; i += 1024) {
        int rec = recs[i];
        int p = atomicAdd(&cur[rec & 255], 1);
        sorted_packed[p] = rec;
    }
}

// ---- fused weights + aggregate (round-8 v3 structure, unchanged) ----------
__global__ __launch_bounds__(256) void gat_aggregate_v3(const __half* __restrict__ H16,
                                                        const int* __restrict__ off_s,
                                                        const int* __restrict__ off_e,
                                                        const int* __restrict__ packed,
                                                        const float* __restrict__ asb,
                                                        const float* __restrict__ adb,
                                                        const float* __restrict__ bias,
                                                        float* __restrict__ OUTF,
                                                        __half* __restrict__ OUTH,
                                                        int n, int mode) {
    int wid = (blockIdx.x * 256 + threadIdx.x) >> 6;
    int lane = threadIdx.x & 63;
    if (wid >= n) return;
    int s = off_s[wid], e = off_e[wid];
    int q = lane >> 4;            // edge slot within the 4-group
    int sub = lane & 15;          // 16B chunk of the 256B row
    int head4 = (sub >> 2) * 4;   // byte offset of this head's score
    int sub16 = sub * 16;
    float adv = adb[(size_t)wid * 4 + (sub >> 2)];
    const char* Hc = reinterpret_cast<const char*>(H16);
    const char* Ac = reinterpret_cast<const char*>(asb);
    float acc[8] = {0, 0, 0, 0, 0, 0, 0, 0};
    float den = 0.f;
    if (s < e) {
        int idx[4]; float sc[4];
        #pragma unroll
        for (int u = 0; u < 4; ++u) {
            int ii = s + q + u * 4;
            int jj = ii < e ? ii : s;
            idx[u] = packed[jj] & 0xFFFFFF00;      // src*256 = H row byte offset
            sc[u] = *reinterpret_cast<const float*>(Ac + (idx[u] >> 4) + head4);
        }
        for (int i = s; i < e; i += 16) {
            uint4 h0 = *reinterpret_cast<const uint4*>(Hc + idx[0] + sub16);
            uint4 h1 = *reinterpret_cast<const uint4*>(Hc + idx[1] + sub16);
            uint4 h2 = *reinterpret_cast<const uint4*>(Hc + idx[2] + sub16);
            uint4 h3 = *reinterpret_cast<const uint4*>(Hc + idx[3] + sub16);
            float w[4];
            #pragma unroll
            for (int u = 0; u < 4; ++u) {
                float ev = sc[u] + adv; ev = fmaxf(ev, 0.2f * ev);
                w[u] = (i + q + u * 4 < e) ? __expf(ev) : 0.f;
            }
            #pragma unroll
            for (int u = 0; u < 4; ++u) {          // prefetch next 4 slots
                int ii = i + 16 + q + u * 4;
                int jj = ii < e ? ii : s;
                idx[u] = packed[jj] & 0xFFFFFF00;
                sc[u] = *reinterpret_cast<const float*>(Ac + (idx[u] >> 4) + head4);
            }
            den += (w[0] + w[1]) + (w[2] + w[3]);
#if HAS_FDOT2
            half2_t w01 = __builtin_bit_cast(half2_t, __builtin_amdgcn_cvt_pkrtz(w[0], w[1]));
            half2_t w23 = __builtin_bit_cast(half2_t, __builtin_amdgcn_cvt_pkrtz(w[2], w[3]));
            const uint* a0 = reinterpret_cast<const uint*>(&h0);
            const uint* a1 = reinterpret_cast<const uint*>(&h1);
            const uint* a2 = reinterpret_cast<const uint*>(&h2);
            const uint* a3 = reinterpret_cast<const uint*>(&h3);
            #pragma unroll
            for (int j = 0; j < 4; ++j) {
                uint p0 = __builtin_amdgcn_perm(a1[j], a0[j], 0x05040100u);
                uint p1 = __builtin_amdgcn_perm(a1[j], a0[j], 0x07060302u);
                uint r0 = __builtin_amdgcn_perm(a3[j], a2[j], 0x05040100u);
                uint r1 = __builtin_amdgcn_perm(a3[j], a2[j], 0x07060302u);
                acc[2*j]   = __builtin_amdgcn_fdot2(__builtin_bit_cast(half2_t, p0), w01,
                             __builtin_amdgcn_fdot2(__builtin_bit_cast(half2_t, r0), w23, acc[2*j],   false), false);
                acc[2*j+1] = __builtin_amdgcn_fdot2(__builtin_bit_cast(half2_t, p1), w01,
                             __builtin_amdgcn_fdot2(__builtin_bit_cast(half2_t, r1), w23, acc[2*j+1], false), false);
            }
#else
            const __half2* pa = reinterpret_cast<const __half2*>(&h0);
            const __half2* pb = reinterpret_cast<const __half2*>(&h1);
            const __half2* pc = reinterpret_cast<const __half2*>(&h2);
            const __half2* pd_ = reinterpret_cast<const __half2*>(&h3);
            #pragma unroll
            for (int j = 0; j < 4; ++j) {
                float2 fa = __half22float2(pa[j]);
                float2 fb = __half22float2(pb[j]);
                float2 fc = __half22float2(pc[j]);
                float2 fd = __half22float2(pd_[j]);
                acc[2*j]   += w[0] * fa.x + w[1] * fb.x + w[2] * fc.x + w[3] * fd.x;
                acc[2*j+1] += w[0] * fa.y + w[1] * fb.y + w[2] * fc.y + w[3] * fd.y;
            }
#endif
        }
    }
    #pragma unroll
    for (int j = 0; j < 8; ++j) acc[j] += __shfl_xor(acc[j], 16);
    den += __shfl_xor(den, 16);
    #pragma unroll
    for (int j = 0; j < 8; ++j) acc[j] += __shfl_xor(acc[j], 32);
    den += __shfl_xor(den, 32);
    if (q == 0) {
        float inv = den > 0.f ? 1.f / den : 0.f;
        float4 b0 = *reinterpret_cast<const float4*>(bias + sub * 8);
        float4 b1 = *reinterpret_cast<const float4*>(bias + sub * 8 + 4);
        float o[8];
        o[0] = acc[0]*inv + b0.x; o[1] = acc[1]*inv + b0.y;
        o[2] = acc[2]*inv + b0.z; o[3] = acc[3]*inv + b0.w;
        o[4] = acc[4]*inv + b1.x; o[5] = acc[5]*inv + b1.y;
        o[6] = acc[6]*inv + b1.z; o[7] = acc[7]*inv + b1.w;
        if (mode) {
            uint4 u;
            __half2* up = reinterpret_cast<__half2*>(&u);
            #pragma unroll
            for (int j = 0; j < 4; ++j)
                up[j] = __floats2half2_rn(fmaxf(o[2*j], 0.f), fmaxf(o[2*j+1], 0.f));
            *reinterpret_cast<uint4*>(OUTH + (size_t)wid * 128 + sub * 8) = u;
        } else {
            *reinterpret_cast<float4*>(OUTF + (size_t)wid * 128 + sub * 8) =
                make_float4(o[0], o[1], o[2], o[3]);
            *reinterpret_cast<float4*>(OUTF + (size_t)wid * 128 + sub * 8 + 4) =
                make_float4(o[4], o[5], o[6], o[7]);
        }
    }
}

// ---------------------------------------------------------------------------
extern "C" void kernel_launch(void* const* d_in, const int* in_sizes, int n_in,
                              void* d_out, int out_size, void* d_ws, size_t ws_size,
                              hipStream_t stream) {
    const float* x        = (const float*)d_in[0];
    const int*   edge     = (const int*)d_in[1];
    const float* W0       = (const float*)d_in[2];
    const float* att_src0 = (const float*)d_in[3];
    const float* att_dst0 = (const float*)d_in[4];
    const float* b0       = (const float*)d_in[5];
    const float* W1       = (const float*)d_in[6];
    const float* att_src1 = (const float*)d_in[7];
    const float* att_dst1 = (const float*)d_in[8];
    const float* b1       = (const float*)d_in[9];
    const int* src = edge;
    const int* dst = edge + N_EDGES;
    float* out = (float*)d_out;

    char* ws = (char*)d_ws;
    size_t o = 0;
    auto alloc = [&](size_t bytes) { char* p = ws + o; o += (bytes + 255) & ~(size_t)255; return p; };
    __half* H16   = (__half*)alloc((size_t)N_NODES * 128 * 2);    // 12.8 MB (persistent)
    float* asb    = (float*)alloc((size_t)N_NODES * 4 * 4);
    float* adb    = (float*)alloc((size_t)N_NODES * 4 * 4);
    int*   off_s  = (int*)alloc((size_t)N_NODES * 4);
    int*   off_e  = (int*)alloc((size_t)N_NODES * 4);
    int*   sorted = (int*)alloc((size_t)NB * CAP * 4);            // 7.0 MB (persistent)
    __half* img0  = (__half*)alloc(32768);                        // swizzled W0 f16 image
    __half* img1  = (__half*)alloc(32768);                        // swizzled W1 f16 image
    // overlay: sort temps, later reused as the f16 layer-0 output
    size_t mark = o;
    int*   bcursor  = (int*)alloc((size_t)NB * 4);                // 784 B
    int*   bucketed = (int*)alloc((size_t)NB * CAP * 4);          // 7.0 MB
    o = mark + (size_t)N_NODES * 128 * 2;                         // reserve h1 region
    __half* h1_16 = (__half*)(ws + mark);                         // 12.8 MB, aliases temps

    // ---- prep: W images + cursor zeroing ----
    prep<<<2, 256, 0, stream>>>(W0, W1, img0, img1, bcursor);

    // ---- layer-0 GEMM ∥ bucket scatter (368 + 400 = 768 blocks, 3/CU) ----
    gemm_mfma<<<GEMM0_BLOCKS + NBLK_S, 256, 0, stream>>>(x, (const __half*)nullptr, 0,
                                                         img0, att_src0, att_dst0,
                                                         H16, asb, adb, N_NODES, GEMM0_BLOCKS,
                                                         src, dst, bcursor, bucketed, 1);
    // ---- within-bucket sort (emits off_start/off_end) ----
    bucket_sort<<<NB, 1024, 0, stream>>>(bucketed, bcursor, sorted, off_s, off_e);

    int agg_blocks = N_NODES / 4;   // 12500, exact

    // ---- layer 0 aggregate (writes f16 + relu) ----
    gat_aggregate_v3<<<agg_blocks, 256, 0, stream>>>(H16, off_s, off_e, sorted, asb, adb, b0,
                                                     (float*)nullptr, h1_16, N_NODES, 1);

    // ---- layer 1 ----
    gemm_mfma<<<GEMM1_BLOCKS, 256, 0, stream>>>((const float*)nullptr, h1_16, 1,
                                                img1, att_src1, att_dst1,
                                                H16, asb, adb, N_NODES, GEMM1_BLOCKS,
                                                (const int*)nullptr, (const int*)nullptr,
                                                (int*)nullptr, (int*)nullptr, 0);
    gat_aggregate_v3<<<agg_blocks, 256, 0, stream>>>(H16, off_s, off_e, sorted, asb, adb, b1,
                                                     out, (__half*)nullptr, N_NODES, 0);
}